// Round 1
// baseline (333.292 us; speedup 1.0000x reference)
//
#include <hip/hip_runtime.h>

#define BB 512
#define TT 30
#define HH 41
#define WFW 40
#define NSEC 9
#define SECLEN 4
#define NF 50
#define KH 6
#define THRESH 23.0f
#define WIN_CNT (NSEC*BB)   // 4608 winner elements precede pots in d_out

// ---------------------------------------------------------------------------
// Kernel 1: pots. One block per (section i, batch b). 256 threads.
// LDS: x slice [t][r][wf] fp32 (43.2 KB) + weights as packed bf16 pairs
//      [kh*WF+wf][fpair] (24 KB). Each thread owns (t, f-pair), computes the
//      4 SECLEN outputs for both f's (8 accumulators, 8 FMA per weight dword).
// ---------------------------------------------------------------------------
__global__ __launch_bounds__(256) void pots_kernel(const float* __restrict__ x,
                                                   const float* __restrict__ W,
                                                   float* __restrict__ out)
{
    const int blk = blockIdx.x;           // i*BB + b
    const int i   = blk / BB;
    const int b   = blk - i * BB;
    const int tid = threadIdx.x;

    __shared__ float    xs[TT * 9 * WFW];       // [t][r][wf], r = h - 4*i, 43200 B
    __shared__ unsigned wl[KH * WFW * (NF/2)];  // [(kh*WF+wf)*25 + fp], 24000 B

    // ---- stage x slice (rows 4i .. 4i+8 for every t), coalesced ----
    const float* xg = x + (size_t)(b * TT) * HH * WFW + (size_t)(i * SECLEN) * WFW;
    for (int idx = tid; idx < TT * 9 * WFW; idx += 256) {
        int t   = idx / (9 * WFW);
        int rem = idx - t * (9 * WFW);          // r*WF + wf
        xs[idx] = xg[(size_t)t * HH * WFW + rem];
    }

    // ---- stage W section as bf16 pairs (f0=2fp low, f0+1 high) ----
    const float* Wg = W + (size_t)i * NF * KH * WFW;
    for (int idx = tid; idx < KH * WFW * (NF/2); idx += 256) {
        int fp = idx % (NF/2);
        int kw = idx / (NF/2);                  // kh*WF + wf
        float w0 = Wg[(2*fp    ) * KH * WFW + kw];
        float w1 = Wg[(2*fp + 1) * KH * WFW + kw];
        // round-to-nearest-even bf16 (values are positive normals ~0.8)
        unsigned b0 = __float_as_uint(w0); b0 = (b0 + 0x7FFFu + ((b0 >> 16) & 1u)) >> 16;
        unsigned b1 = __float_as_uint(w1); b1 = (b1 + 0x7FFFu + ((b1 >> 16) & 1u)) >> 16;
        wl[kw * (NF/2) + fp] = b0 | (b1 << 16);
    }
    __syncthreads();

    float* po = out + WIN_CNT + (size_t)blk * TT * NF * SECLEN;

    for (int p = tid; p < TT * (NF/2); p += 256) {
        int t  = p / (NF/2);
        int fp = p - t * (NF/2);
        float a0[SECLEN] = {0.f, 0.f, 0.f, 0.f};
        float a1[SECLEN] = {0.f, 0.f, 0.f, 0.f};
        const float*    xt = &xs[t * 9 * WFW];
        const unsigned* wp = &wl[fp];

        for (int kh = 0; kh < KH; ++kh) {
            #pragma unroll 4
            for (int wf = 0; wf < WFW; ++wf) {
                unsigned w2 = wp[(kh * WFW + wf) * (NF/2)];
                float w0 = __uint_as_float(w2 << 16);
                float w1 = __uint_as_float(w2 & 0xFFFF0000u);
                float x0 = xt[(kh + 0) * WFW + wf];
                float x1 = xt[(kh + 1) * WFW + wf];
                float x2 = xt[(kh + 2) * WFW + wf];
                float x3 = xt[(kh + 3) * WFW + wf];
                a0[0] = fmaf(x0, w0, a0[0]);
                a0[1] = fmaf(x1, w0, a0[1]);
                a0[2] = fmaf(x2, w0, a0[2]);
                a0[3] = fmaf(x3, w0, a0[3]);
                a1[0] = fmaf(x0, w1, a1[0]);
                a1[1] = fmaf(x1, w1, a1[1]);
                a1[2] = fmaf(x2, w1, a1[2]);
                a1[3] = fmaf(x3, w1, a1[3]);
            }
        }
        float4* dst = (float4*)(po + ((size_t)t * NF + 2 * fp) * SECLEN);
        dst[0] = make_float4(a0[0], a0[1], a0[2], a0[3]);
        dst[1] = make_float4(a1[0], a1[1], a1[2], a1[3]);
    }
}

// ---------------------------------------------------------------------------
// Kernel 2: winners. One wave per (i,b); lane = f. Replicates the reference
// formula exactly: s = per-(t,f) spike bit; c=popcount; first=min(30-c,29);
// fv = bit(first); v = 30 * any(fv); total = c*(fv+v); first-occurrence argmax.
// ---------------------------------------------------------------------------
__global__ __launch_bounds__(64) void win_kernel(float* __restrict__ out)
{
    const int blk = blockIdx.x;           // i*BB + b
    const int f   = threadIdx.x;          // lane 0..63, f valid < 50
    const float* po = out + WIN_CNT + (size_t)blk * TT * NF * SECLEN;

    unsigned mask = 0u;
    if (f < NF) {
        for (int t = 0; t < TT; ++t) {
            const float4 v = *(const float4*)(po + ((size_t)t * NF + f) * SECLEN);
            float m = fmaxf(fmaxf(v.x, v.y), fmaxf(v.z, v.w));
            if (m >= THRESH) mask |= (1u << t);
        }
    }
    int c     = __popc(mask);
    int first = 30 - c; if (first > 29) first = 29;
    int fv    = (f < NF) ? (int)((mask >> first) & 1u) : 0;
    unsigned long long bal = __ballot(fv != 0);
    int v30 = (bal != 0ull) ? 30 : 0;
    int tot = (f < NF) ? c * (fv + v30) : -1;
    int idx = f;
    // butterfly max, tie -> smaller index (matches jnp.argmax first-occurrence)
    for (int off = 32; off > 0; off >>= 1) {
        int ot = __shfl_xor(tot, off);
        int oi = __shfl_xor(idx, off);
        if (ot > tot || (ot == tot && oi < idx)) { tot = ot; idx = oi; }
    }
    if (f == 0) out[blk] = (float)((tot > 0) ? idx : -1);
}

extern "C" void kernel_launch(void* const* d_in, const int* in_sizes, int n_in,
                              void* d_out, int out_size, void* d_ws, size_t ws_size,
                              hipStream_t stream)
{
    const float* x = (const float*)d_in[0];
    const float* W = (const float*)d_in[1];
    float* out = (float*)d_out;

    pots_kernel<<<NSEC * BB, 256, 0, stream>>>(x, W, out);
    win_kernel <<<NSEC * BB,  64, 0, stream>>>(out);
}

// Round 2
// 74.525 us; speedup vs baseline: 4.4722x; 4.4722x over previous
//
#include <hip/hip_runtime.h>

#define BB 512
#define TT 30
#define HH 41
#define WFW 40
#define NSEC 9
#define SECLEN 4
#define NF 50
#define KH 6
#define THRESH 23.0f
#define NBT (BB*TT)                 // 15360 (b,t) rows; 15360 % 16 == 0
#define WIN_CNT (NSEC*BB)           // 4608 winners precede pots in d_out
#define NBT_BLK 16                  // (b,t) pairs per block
#define SLAB 3344                   // bytes per bt slab in LDS (1672 bf16; 1640 data + pad)
#define WSW_BYTES (NSEC*4*8*64*16)  // 294912: W as B-fragments, bf16
#define SPK_BYTES (NSEC*NBT*NF)     // 6912000: spike byte per (i,bt,f)

typedef __attribute__((ext_vector_type(8))) short short8;   // 8 bf16 = 4 VGPR
typedef __attribute__((ext_vector_type(4))) float f32x4;

// ---------------------------------------------------------------------------
// Pre-kernel: W fp32 -> bf16 B-fragment layout in ws.
// Fragment (i,nt,kc): lane l holds B[k][f], f = nt*16+(l&15), k = 32kc+8*(l>>4)+j.
// Zero for f>=50 or k>=240 (K padded 240->256, N padded 50->64).
// ---------------------------------------------------------------------------
__global__ __launch_bounds__(256) void wconv_kernel(const float* __restrict__ W,
                                                    unsigned char* __restrict__ wsw)
{
    int gid  = blockIdx.x * 256 + threadIdx.x;      // 18432 total
    int frag = gid >> 6, l = gid & 63;
    int i    = frag >> 5, rem = frag & 31;
    int nt   = rem >> 3,  kc  = rem & 7;
    int f    = nt * 16 + (l & 15);
    int kb   = kc * 32 + (l >> 4) * 8;
    unsigned d0 = 0, d1 = 0, d2 = 0, d3 = 0;
    if (f < NF && kb < KH * WFW) {
        const float* src = W + (size_t)(i * NF + f) * (KH * WFW) + kb;
        float4 v0 = ((const float4*)src)[0];
        float4 v1 = ((const float4*)src)[1];
        float vv[8] = {v0.x, v0.y, v0.z, v0.w, v1.x, v1.y, v1.z, v1.w};
        unsigned r[8];
        #pragma unroll
        for (int j = 0; j < 8; ++j) {
            unsigned a = __float_as_uint(vv[j]);
            r[j] = (a + 0x7FFFu + ((a >> 16) & 1u)) >> 16;   // RNE to bf16
        }
        d0 = r[0] | (r[1] << 16); d1 = r[2] | (r[3] << 16);
        d2 = r[4] | (r[5] << 16); d3 = r[6] | (r[7] << 16);
    }
    ((uint4*)wsw)[gid] = make_uint4(d0, d1, d2, d3);
}

// ---------------------------------------------------------------------------
// Main kernel: block = 16 (b,t) pairs, 4 waves. Stage full H=41 x-rows as
// bf16 once; loop 9 sections: B-frags in regs (32x4 VGPR), per K-chunk one
// ds_read_b128 A-frag + 4 MFMA. D layout: col=l&15 (f), rows 4*(l>>4)+reg
// = the 4 SECLEN values of one (bt,f) -> float4 store + spike byte.
// ---------------------------------------------------------------------------
template<bool WRITE_SPK>
__global__ __launch_bounds__(256, 2) void pots_mfma(const float* __restrict__ x,
                                                    const unsigned char* __restrict__ wsw,
                                                    float* __restrict__ out,
                                                    unsigned char* __restrict__ spk)
{
    __shared__ alignas(16) char xs[NBT_BLK * SLAB];   // 53504 B
    const int tid = threadIdx.x;
    const int bt0 = blockIdx.x * NBT_BLK;

    // ---- stage x (16 bt x 1640 floats) -> bf16, coalesced float4 reads ----
    for (int it = 0; it < 26; ++it) {
        int idx = tid + it * 256;                     // float4 index, 6560 total
        if (idx < 16 * 410) {
            int bt = idx / 410, pos = idx - bt * 410;
            const float4 v = *(const float4*)(x + (size_t)(bt0 + bt) * (HH * WFW) + pos * 4);
            unsigned u0 = __float_as_uint(v.x), u1 = __float_as_uint(v.y);
            unsigned u2 = __float_as_uint(v.z), u3 = __float_as_uint(v.w);
            // x in {0,1}: truncation to bf16 is exact
            uint2 p;
            p.x = (u0 >> 16) | (u1 & 0xFFFF0000u);
            p.y = (u2 >> 16) | (u3 & 0xFFFF0000u);
            *(uint2*)(xs + bt * SLAB + pos * 8) = p;
        }
    }
    if (tid < 64) {   // zero pad elems 1640..1671 of each slab (i=8 K-pad reads)
        int bt = tid >> 2, part = tid & 3;
        *(uint4*)(xs + bt * SLAB + 3280 + part * 16) = make_uint4(0, 0, 0, 0);
    }
    __syncthreads();

    const int l   = tid & 63, wid = tid >> 6;
    const int q   = l >> 4;                 // k-block (A/B), bt-in-wave (D)
    const int f16 = l & 15;
    const int bta = wid * 4 + ((l >> 2) & 3);        // A-side bt (row = l&15)
    const int s   = l & 3;                           // A-side s
    const int btd = bt0 + wid * 4 + q;               // D-side bt (global)
    const unsigned abase0 = bta * SLAB + s * 80 + q * 16;

    #pragma unroll 1
    for (int i = 0; i < NSEC; ++i) {
        // B fragments for this section (L2-resident ws), 128 VGPR
        short8 bfr[32];
        const unsigned char* wbase = wsw + (size_t)i * 32768 + l * 16;
        #pragma unroll
        for (int nt = 0; nt < 4; ++nt)
            #pragma unroll
            for (int kc = 0; kc < 8; ++kc)
                bfr[nt * 8 + kc] = *(const short8*)(wbase + (nt * 8 + kc) * 1024);

        f32x4 acc[4] = {{0,0,0,0},{0,0,0,0},{0,0,0,0},{0,0,0,0}};
        const unsigned abase = abase0 + i * 320;     // slab elem = 160i + 40s + k
        #pragma unroll
        for (int kc = 0; kc < 8; ++kc) {
            short8 a = *(const short8*)(xs + abase + kc * 64);
            #pragma unroll
            for (int nt = 0; nt < 4; ++nt)
                acc[nt] = __builtin_amdgcn_mfma_f32_16x16x32_bf16(a, bfr[nt * 8 + kc], acc[nt], 0, 0, 0);
        }

        #pragma unroll
        for (int nt = 0; nt < 4; ++nt) {
            int f = nt * 16 + f16;
            if (f < NF) {
                size_t o = (size_t)(i * NBT + btd) * NF + f;
                *(float4*)(out + WIN_CNT + o * 4) =
                    make_float4(acc[nt][0], acc[nt][1], acc[nt][2], acc[nt][3]);
                if (WRITE_SPK) {
                    float m = fmaxf(fmaxf(acc[nt][0], acc[nt][1]),
                                    fmaxf(acc[nt][2], acc[nt][3]));
                    spk[o] = (m >= THRESH) ? (unsigned char)1 : (unsigned char)0;
                }
            }
        }
    }
}

// ---------------------------------------------------------------------------
// Winners from spike bytes (6.9 MB instead of 110.6 MB pot re-read).
// Same verified formula: c=popcnt, first=min(30-c,29), fv=bit(first),
// total=c*(fv+30*any(fv)), first-occurrence argmax, -1 if total<=0.
// ---------------------------------------------------------------------------
__global__ __launch_bounds__(64) void win_spk(const unsigned char* __restrict__ spk,
                                              float* __restrict__ out)
{
    const int blk = blockIdx.x;              // i*BB + b
    const int i = blk / BB, b = blk - i * BB;
    const int f = threadIdx.x;
    unsigned mask = 0u;
    if (f < NF) {
        const unsigned char* p = spk + (size_t)(i * NBT + b * TT) * NF + f;
        for (int t = 0; t < TT; ++t)
            if (p[(size_t)t * NF]) mask |= (1u << t);
    }
    int c     = __popc(mask);
    int first = TT - c; if (first > TT - 1) first = TT - 1;
    int fv    = (f < NF) ? (int)((mask >> first) & 1u) : 0;
    unsigned long long bal = __ballot(fv != 0);
    int v30 = (bal != 0ull) ? TT : 0;
    int tot = (f < NF) ? c * (fv + v30) : -1;
    int idx = f;
    for (int off = 32; off > 0; off >>= 1) {
        int ot = __shfl_xor(tot, off);
        int oi = __shfl_xor(idx, off);
        if (ot > tot || (ot == tot && oi < idx)) { tot = ot; idx = oi; }
    }
    if (f == 0) out[blk] = (float)((tot > 0) ? idx : -1);
}

// Fallback: winners straight from pots (if ws too small for spike buffer).
__global__ __launch_bounds__(64) void win_pots(float* __restrict__ out)
{
    const int blk = blockIdx.x;
    const int f   = threadIdx.x;
    const float* po = out + WIN_CNT + (size_t)blk * TT * NF * SECLEN;
    unsigned mask = 0u;
    if (f < NF) {
        for (int t = 0; t < TT; ++t) {
            const float4 v = *(const float4*)(po + ((size_t)t * NF + f) * SECLEN);
            float m = fmaxf(fmaxf(v.x, v.y), fmaxf(v.z, v.w));
            if (m >= THRESH) mask |= (1u << t);
        }
    }
    int c     = __popc(mask);
    int first = TT - c; if (first > TT - 1) first = TT - 1;
    int fv    = (f < NF) ? (int)((mask >> first) & 1u) : 0;
    unsigned long long bal = __ballot(fv != 0);
    int v30 = (bal != 0ull) ? TT : 0;
    int tot = (f < NF) ? c * (fv + v30) : -1;
    int idx = f;
    for (int off = 32; off > 0; off >>= 1) {
        int ot = __shfl_xor(tot, off);
        int oi = __shfl_xor(idx, off);
        if (ot > tot || (ot == tot && oi < idx)) { tot = ot; idx = oi; }
    }
    if (f == 0) out[blk] = (float)((tot > 0) ? idx : -1);
}

extern "C" void kernel_launch(void* const* d_in, const int* in_sizes, int n_in,
                              void* d_out, int out_size, void* d_ws, size_t ws_size,
                              hipStream_t stream)
{
    const float* x = (const float*)d_in[0];
    const float* W = (const float*)d_in[1];
    float* out = (float*)d_out;
    unsigned char* wsw = (unsigned char*)d_ws;
    unsigned char* spk = wsw + WSW_BYTES;
    const bool use_spk = ws_size >= (size_t)(WSW_BYTES + SPK_BYTES);

    wconv_kernel<<<(NSEC*4*8*64) / 256, 256, 0, stream>>>(W, wsw);
    if (use_spk) {
        pots_mfma<true><<<NBT / NBT_BLK, 256, 0, stream>>>(x, wsw, out, spk);
        win_spk<<<NSEC * BB, 64, 0, stream>>>(spk, out);
    } else {
        pots_mfma<false><<<NBT / NBT_BLK, 256, 0, stream>>>(x, wsw, out, nullptr);
        win_pots<<<NSEC * BB, 64, 0, stream>>>(out);
    }
}

// Round 3
// 61.873 us; speedup vs baseline: 5.3867x; 1.2045x over previous
//
#include <hip/hip_runtime.h>

#define BB 512
#define TT 30
#define HH 41
#define WFW 40
#define NSEC 9
#define SECLEN 4
#define NF 50
#define KH 6
#define THRESH 23.0f
#define NBT (BB*TT)                 // 15360 (b,t) rows
#define WIN_CNT (NSEC*BB)           // 4608 winners precede pots in d_out
#define BT_BLK 64                   // bt rows per block
#define NBTBLK (NBT/BT_BLK)         // 240 (== 0 mod 8 -> same-XCD x reuse across sections)
#define SLAB 752                    // bytes per bt slab: 376 bf16 (360 data + 16 K-pad)
#define WSW_BYTES (NSEC*4*8*64*16)  // 294912: W as B-fragments, bf16
#define SPK_BYTES (NSEC*NBT*NF)     // 6912000: spike byte per (i,bt,f)

typedef __attribute__((ext_vector_type(8))) short short8;   // 8 bf16 = 4 VGPR
typedef __attribute__((ext_vector_type(4))) float f32x4;

// ---------------------------------------------------------------------------
// Pre-kernel: W fp32 -> bf16 B-fragment layout in ws (unchanged from R2).
// Fragment (i,nt,kc): lane l holds B[k][f], f = nt*16+(l&15), k = 32kc+8*(l>>4)+j.
// ---------------------------------------------------------------------------
__global__ __launch_bounds__(256) void wconv_kernel(const float* __restrict__ W,
                                                    unsigned char* __restrict__ wsw)
{
    int gid  = blockIdx.x * 256 + threadIdx.x;      // 18432 total
    int frag = gid >> 6, l = gid & 63;
    int i    = frag >> 5, rem = frag & 31;
    int nt   = rem >> 3,  kc  = rem & 7;
    int f    = nt * 16 + (l & 15);
    int kb   = kc * 32 + (l >> 4) * 8;
    unsigned d0 = 0, d1 = 0, d2 = 0, d3 = 0;
    if (f < NF && kb < KH * WFW) {
        const float* src = W + (size_t)(i * NF + f) * (KH * WFW) + kb;
        float4 v0 = ((const float4*)src)[0];
        float4 v1 = ((const float4*)src)[1];
        float vv[8] = {v0.x, v0.y, v0.z, v0.w, v1.x, v1.y, v1.z, v1.w};
        unsigned r[8];
        #pragma unroll
        for (int j = 0; j < 8; ++j) {
            unsigned a = __float_as_uint(vv[j]);
            r[j] = (a + 0x7FFFu + ((a >> 16) & 1u)) >> 16;   // RNE to bf16
        }
        d0 = r[0] | (r[1] << 16); d1 = r[2] | (r[3] << 16);
        d2 = r[4] | (r[5] << 16); d3 = r[6] | (r[7] << 16);
    }
    ((uint4*)wsw)[gid] = make_uint4(d0, d1, d2, d3);
}

// ---------------------------------------------------------------------------
// Main kernel: block = (section i, 64 bt). 4 waves; wave owns 16 bt as 4
// M-tiles. kc-outer loop: 4 B-frag loads then 4 x (ds_read_b128 A + 4 MFMA)
// -> 32 B loads amortized over 128 MFMA per wave. acc[4][4] fully unrolled.
// ---------------------------------------------------------------------------
template<bool WRITE_SPK>
__global__ __launch_bounds__(256, 4) void pots_mfma(const float* __restrict__ x,
                                                    const unsigned char* __restrict__ wsw,
                                                    float* __restrict__ out,
                                                    unsigned char* __restrict__ spk)
{
    __shared__ alignas(16) char xs[BT_BLK * SLAB];   // 48128 B
    const int tid = threadIdx.x;
    const int blk = blockIdx.x;
    const int i   = blk / NBTBLK;                    // section
    const int bt0 = (blk - i * NBTBLK) * BT_BLK;

    // ---- stage x rows 4i..4i+8 (360 floats/bt) -> bf16 slabs, coalesced ----
    const float* xg = x + (size_t)bt0 * (HH * WFW) + i * SECLEN * WFW;
    #pragma unroll
    for (int it = 0; it < 23; ++it) {
        int idx = tid + it * 256;                    // float4 index, 64*90 total
        if (idx < BT_BLK * 90) {
            int bt = idx / 90, pos = idx - bt * 90;
            const float4 v = *(const float4*)(xg + (size_t)bt * (HH * WFW) + pos * 4);
            unsigned u0 = __float_as_uint(v.x), u1 = __float_as_uint(v.y);
            unsigned u2 = __float_as_uint(v.z), u3 = __float_as_uint(v.w);
            uint2 p;                                 // x in {0,1}: truncation exact
            p.x = (u0 >> 16) | (u1 & 0xFFFF0000u);
            p.y = (u2 >> 16) | (u3 & 0xFFFF0000u);
            *(uint2*)(xs + bt * SLAB + pos * 8) = p;
        }
    }
    if (tid < 128) {   // zero K-pad elems 360..375 of each slab
        int bt = tid >> 1, part = tid & 1;
        *(uint4*)(xs + bt * SLAB + 720 + part * 16) = make_uint4(0, 0, 0, 0);
    }
    __syncthreads();

    const int l   = tid & 63, wid = tid >> 6;
    const int q   = l >> 4;                          // A: k-subblock; D: bt-in-tile
    const int f16 = l & 15;
    // A-frag: row (l&15) = 4*bt_in + s
    const unsigned abase = (unsigned)(wid * 16 + ((l >> 2) & 3)) * SLAB
                         + 80u * (l & 3) + 16u * q;

    f32x4 acc[4][4];
    #pragma unroll
    for (int r = 0; r < 4; ++r)
        #pragma unroll
        for (int nt = 0; nt < 4; ++nt)
            acc[r][nt] = (f32x4){0.f, 0.f, 0.f, 0.f};

    const unsigned char* wbase = wsw + (size_t)i * 32768 + (size_t)l * 16;
    #pragma unroll
    for (int kc = 0; kc < 8; ++kc) {
        short8 b0 = *(const short8*)(wbase + (0 * 8 + kc) * 1024);
        short8 b1 = *(const short8*)(wbase + (1 * 8 + kc) * 1024);
        short8 b2 = *(const short8*)(wbase + (2 * 8 + kc) * 1024);
        short8 b3 = *(const short8*)(wbase + (3 * 8 + kc) * 1024);
        #pragma unroll
        for (int r = 0; r < 4; ++r) {
            short8 a = *(const short8*)(xs + abase + r * 4 * SLAB + kc * 64);
            acc[r][0] = __builtin_amdgcn_mfma_f32_16x16x32_bf16(a, b0, acc[r][0], 0, 0, 0);
            acc[r][1] = __builtin_amdgcn_mfma_f32_16x16x32_bf16(a, b1, acc[r][1], 0, 0, 0);
            acc[r][2] = __builtin_amdgcn_mfma_f32_16x16x32_bf16(a, b2, acc[r][2], 0, 0, 0);
            acc[r][3] = __builtin_amdgcn_mfma_f32_16x16x32_bf16(a, b3, acc[r][3], 0, 0, 0);
        }
    }

    // D layout: col=f16 (f), rows 4q+reg = (bt_in=q, s=reg)
    #pragma unroll
    for (int r = 0; r < 4; ++r) {
        const int btd = bt0 + wid * 16 + r * 4 + q;
        const size_t base = ((size_t)i * NBT + btd) * NF;
        #pragma unroll
        for (int nt = 0; nt < 4; ++nt) {
            int f = nt * 16 + f16;
            if (f < NF) {
                size_t o = base + f;
                *(float4*)(out + WIN_CNT + o * 4) =
                    make_float4(acc[r][nt][0], acc[r][nt][1], acc[r][nt][2], acc[r][nt][3]);
                if (WRITE_SPK) {
                    float m = fmaxf(fmaxf(acc[r][nt][0], acc[r][nt][1]),
                                    fmaxf(acc[r][nt][2], acc[r][nt][3]));
                    spk[o] = (m >= THRESH) ? (unsigned char)1 : (unsigned char)0;
                }
            }
        }
    }
}

// ---------------------------------------------------------------------------
// Winners from spike bytes. Verified formula: c=popcnt, first=min(30-c,29),
// fv=bit(first), total=c*(fv+30*any(fv)), first-occurrence argmax, -1 if <=0.
// ---------------------------------------------------------------------------
__global__ __launch_bounds__(64) void win_spk(const unsigned char* __restrict__ spk,
                                              float* __restrict__ out)
{
    const int blk = blockIdx.x;              // i*BB + b
    const int i = blk / BB, b = blk - i * BB;
    const int f = threadIdx.x;
    unsigned mask = 0u;
    if (f < NF) {
        const unsigned char* p = spk + (size_t)(i * NBT + b * TT) * NF + f;
        for (int t = 0; t < TT; ++t)
            if (p[(size_t)t * NF]) mask |= (1u << t);
    }
    int c     = __popc(mask);
    int first = TT - c; if (first > TT - 1) first = TT - 1;
    int fv    = (f < NF) ? (int)((mask >> first) & 1u) : 0;
    unsigned long long bal = __ballot(fv != 0);
    int v30 = (bal != 0ull) ? TT : 0;
    int tot = (f < NF) ? c * (fv + v30) : -1;
    int idx = f;
    for (int off = 32; off > 0; off >>= 1) {
        int ot = __shfl_xor(tot, off);
        int oi = __shfl_xor(idx, off);
        if (ot > tot || (ot == tot && oi < idx)) { tot = ot; idx = oi; }
    }
    if (f == 0) out[blk] = (float)((tot > 0) ? idx : -1);
}

// Fallback: winners straight from pots (if ws too small for spike buffer).
__global__ __launch_bounds__(64) void win_pots(float* __restrict__ out)
{
    const int blk = blockIdx.x;
    const int f   = threadIdx.x;
    const float* po = out + WIN_CNT + (size_t)blk * TT * NF * SECLEN;
    unsigned mask = 0u;
    if (f < NF) {
        for (int t = 0; t < TT; ++t) {
            const float4 v = *(const float4*)(po + ((size_t)t * NF + f) * SECLEN);
            float m = fmaxf(fmaxf(v.x, v.y), fmaxf(v.z, v.w));
            if (m >= THRESH) mask |= (1u << t);
        }
    }
    int c     = __popc(mask);
    int first = TT - c; if (first > TT - 1) first = TT - 1;
    int fv    = (f < NF) ? (int)((mask >> first) & 1u) : 0;
    unsigned long long bal = __ballot(fv != 0);
    int v30 = (bal != 0ull) ? TT : 0;
    int tot = (f < NF) ? c * (fv + v30) : -1;
    int idx = f;
    for (int off = 32; off > 0; off >>= 1) {
        int ot = __shfl_xor(tot, off);
        int oi = __shfl_xor(idx, off);
        if (ot > tot || (ot == tot && oi < idx)) { tot = ot; idx = oi; }
    }
    if (f == 0) out[blk] = (float)((tot > 0) ? idx : -1);
}

extern "C" void kernel_launch(void* const* d_in, const int* in_sizes, int n_in,
                              void* d_out, int out_size, void* d_ws, size_t ws_size,
                              hipStream_t stream)
{
    const float* x = (const float*)d_in[0];
    const float* W = (const float*)d_in[1];
    float* out = (float*)d_out;
    unsigned char* wsw = (unsigned char*)d_ws;
    unsigned char* spk = wsw + WSW_BYTES;
    const bool use_spk = ws_size >= (size_t)(WSW_BYTES + SPK_BYTES);

    wconv_kernel<<<(NSEC*4*8*64) / 256, 256, 0, stream>>>(W, wsw);
    if (use_spk) {
        pots_mfma<true><<<NSEC * NBTBLK, 256, 0, stream>>>(x, wsw, out, spk);
        win_spk<<<NSEC * BB, 64, 0, stream>>>(spk, out);
    } else {
        pots_mfma<false><<<NSEC * NBTBLK, 256, 0, stream>>>(x, wsw, out, nullptr);
        win_pots<<<NSEC * BB, 64, 0, stream>>>(out);
    }
}